// Round 1
// 14041.502 us; speedup vs baseline: 1.7082x; 1.7082x over previous
//
#include <hip/hip_runtime.h>
#include <stdint.h>

// ============================================================================
// RecurrentAutoEncoder (2-layer LSTM enc + 2-layer LSTM dec + FC).
// ALL inputs/outputs are FP32 (per reference). Internally: bf16 MFMA
// fragments, fp32 accum.
//   Phase A (coop, 256 WGs): enc0 --ring(4)--> enc1  (enc1 seq discarded)
//   Phase B (coop, 256 WGs): dec0 --ring(4)--> dec1 --(delay 4)--> fused FC
// h buffers: 8-plane bf16 rings; enc->dec h_T handoff free (512 % 8 == 0).
//
// v2 SYNC (this round): the old single-counter fetch_add(RELEASE)/acquire
// scheme cost ~24 us/step: agent-release emits buffer_wbl2 sc1 (L2 dirty
// writeback) per WG per step, agent-acquire emits buffer_inv sc1 (L2
// invalidate -> 930 MB refetch), and 64 same-line RMWs serialize at IF$.
// Replaced with:
//   * per-WG flag words (no RMW, no same-line contention): flags[g][u]=t+1
//     via relaxed agent-scope store (sc0 sc1 write-through).
//   * ALL cross-WG data (h-rings, layer rings, FC input) uses relaxed
//     agent-scope loads/stores (sc0 sc1) -> no wbl2 on release, no inv on
//     acquire. Release order: __syncthreads() drains vmcnt for every wave
//     before the flag store.
//   * consumer wait = 64-lane parallel poll (lane ln polls flag ln) + __all.
//   * x-part MFMAs (global fp32, no cross-WG dep) hoisted before the wait.
// Flag arrays reused across phases via fb base (phase A ends at 512).
// d_ws footprint unchanged: 3.1 MiB.
// ============================================================================

using bf16x8 = __attribute__((ext_vector_type(8))) short;   // 8 bf16 = 4 VGPR
using f32x16 = __attribute__((ext_vector_type(16))) float;  // 32x32 mfma acc
using f32x4  = __attribute__((ext_vector_type(4))) float;   // 16x16 mfma acc

#define MFMA32(a, b, c) __builtin_amdgcn_mfma_f32_32x32x16_bf16((a), (b), (c), 0, 0, 0)
#define MFMA16(a, b, c) __builtin_amdgcn_mfma_f32_16x16x32_bf16((a), (b), (c), 0, 0, 0)

static __device__ __forceinline__ uint16_t f2bf(float f) {
  union { float f; uint32_t u; } v; v.f = f;
  uint32_t u = v.u;
  return (uint16_t)((u + 0x7fffu + ((u >> 16) & 1u)) >> 16);  // RNE
}
static __device__ __forceinline__ float sigm(float x) { return 1.0f / (1.0f + __expf(-x)); }
static __device__ __forceinline__ float tanh_f(float x) { return 2.0f / (1.0f + __expf(-2.0f * x)) - 1.0f; }

static __device__ __forceinline__ bf16x8 cvt8(const float* p) {
  bf16x8 r;
#pragma unroll
  for (int i = 0; i < 8; ++i) { uint16_t b = f2bf(p[i]); r[i] = (short)b; }
  return r;
}

// ---- device-coherent (sc0 sc1) helpers: bypass stale L1/L2, no wbl2/inv ----
static __device__ __forceinline__ uint32_t aldf(const uint32_t* p) {
  return __hip_atomic_load(p, __ATOMIC_RELAXED, __HIP_MEMORY_SCOPE_AGENT);
}
static __device__ __forceinline__ bf16x8 ald16(const uint16_t* p) {
  union { uint64_t q[2]; bf16x8 v; } r;
  const uint64_t* q = (const uint64_t*)p;
  r.q[0] = __hip_atomic_load(q, __ATOMIC_RELAXED, __HIP_MEMORY_SCOPE_AGENT);
  r.q[1] = __hip_atomic_load(q + 1, __ATOMIC_RELAXED, __HIP_MEMORY_SCOPE_AGENT);
  return r.v;
}
static __device__ __forceinline__ void ast32(uint16_t* p, uint32_t v) {
  __hip_atomic_store((uint32_t*)p, v, __ATOMIC_RELAXED, __HIP_MEMORY_SCOPE_AGENT);
}

// ---------------- workspace layout (bytes); total 3,146,752 B ----------------
static const size_t OFF_FLG = 0;                  // [4][64] u32 per-WG step flags
static const size_t OFF_HB0 = 1024;               // [8][128][512] bf16 h-ring (enc0/dec0)
static const size_t OFF_HB1 = 1024 + 1048576;     // [8][128][512] bf16 h-ring (enc1/dec1)
static const size_t OFF_E0R = 1024 + 2097152;     // [4][128][512] bf16 ring enc0->enc1
static const size_t OFF_D0R = 1024 + 2621440;     // [4][128][512] bf16 ring dec0->dec1

// ---------------- init: zero flags + h-ring plane0 (h_{-1}=0) ------------
__global__ void init_kernel(uint32_t* flg, uint32_t* h0a, uint32_t* h0b) {
  int i = (int)blockIdx.x * 256 + (int)threadIdx.x;
  if (i < 256) flg[i] = 0;
  for (int j = i; j < 32768; j += (int)gridDim.x * 256) { h0a[j] = 0; h0b[j] = 0; }
}

// ---------------- pipelined persistent LSTM layer kernel ----------------
struct PJob {
  const float* whh;       // [2048][512] fp32
  const float* wih;       // [2048][KX] fp32
  const float* bih;       // [2048] fp32
  const float* bhh;       // [2048] fp32
  const float* xf;        // fp32 x [128][512][KX] (enc0/dec0) or null
  const uint16_t* xring;  // [4][128][512] bf16 ring (enc1/dec1) or null
  uint16_t* hring;        // [8][128][512] bf16; plane0 = h_{-1}
  const float* c0;        // [128][512] fp32 or null (zeros)
  uint16_t* ringout;      // [4][128][512] bf16 or null
  uint32_t* fown;         // [2][64] own per-WG flags (per batch-group)
  const uint32_t* fprod;  // [2][64] producer flags or null (ring input ready)
  const uint32_t* fcons;  // [2][64] consumer flags or null (ring free / FC src)
  const float* fcw;       // [128][512] fp32 or null (dec0 only)
  const float* fcb;       // [128] fp32
  const uint16_t* fchr;   // dec1 h-ring (FC input)
  float* out;             // d_out [128][512][128] fp32
  int KX;                 // 128 or 512
  int shift;              // 1 for dec0 (input = x shifted right one step)
  int tsteps;             // 512, or 516 for dec0 (FC drain tail)
  uint32_t fb;            // flag base: 0 (phase A) or 512 (phase B)
};

__global__ void __launch_bounds__(256, 1) lstm_pipe(PJob j0, PJob j1) {
  const PJob J = ((int)blockIdx.x < 128) ? j0 : j1;
  const int lb = (int)blockIdx.x & 127;
  const int bg = lb >> 6, u = lb & 63, b0 = bg * 64;
  const int tid = (int)threadIdx.x;
  const int wv = tid >> 6, ln = tid & 63;

  __shared__ __align__(16) uint16_t Wl[40960];  // 64K rec weights + 16K fcW (80 KiB)
  __shared__ float gb[2][64][33];               // k-partial gates (+1 pad)
  __shared__ float cst[64][9];                  // fp32 cell state (+1 pad)

  const int KX = J.KX;
  const int NTX = KX >> 5;          // x k-blocks per k-half (4 or 16)
  const int HS = (16 + NTX) * 512;  // packed elems per k-half

  // ---- gather [Whh ; Wih] chunk u from global fp32 -> LDS bf16 MFMA-B frags
  {
    const int nfrag = (2 * HS) >> 3;
    for (int f = tid; f < nfrag; f += 256) {
      int lane = f & 63;
      int kt2 = f >> 6;                       // kh*(16+NTX) + kt
      int kh = (kt2 >= 16 + NTX) ? 1 : 0;
      int kt = kt2 - kh * (16 + NTX);
      int col = lane & 31;
      int wrow = ((col >> 3) << 9) + (u << 3) + (col & 7);
      int m = (kt << 4) + ((lane >> 5) << 3);
      const float* src = (m < 256)
          ? J.whh + (size_t)wrow * 512 + (kh << 8) + m
          : J.wih + (size_t)wrow * KX + kh * (KX >> 1) + (m - 256);
      union { uint16_t h[8]; ulonglong2 v; } tmp;
#pragma unroll
      for (int j = 0; j < 8; ++j) tmp.h[j] = f2bf(src[j]);
      *(ulonglong2*)(Wl + (size_t)f * 8) = tmp.v;
    }
  }

  // FC assignment: dec0 WGs with u<8; wave wv owns out tile (ftr, ftc)
  const int isfc = (J.fcw != nullptr) && (u < 8);
  const int wgti = bg * 8 + u;             // 0..15
  const int ftc = wgti & 7;
  const int ftr = 2 * wv + (wgti >> 3);    // 0..7
  const int fcol = ftc * 16 + (ln & 15);
  const int farow = ftr * 16 + (ln & 15);
  float fbv = 0.0f;
  if (isfc) {
    fbv = J.fcb[fcol];
    for (int f = tid; f < 1024; f += 256) {
      int lane = f & 63, kt = f >> 6;
      int row = ftc * 16 + (lane & 15);
      int k = (kt << 5) + ((lane >> 4) << 3);
      const float* src = J.fcw + (size_t)row * 512 + k;
      union { uint16_t h[8]; ulonglong2 v; } tmp;
#pragma unroll
      for (int j = 0; j < 8; ++j) tmp.h[j] = f2bf(src[j]);
      *(ulonglong2*)(Wl + 32768 + (size_t)f * 8) = tmp.v;
    }
  }

  // ---- per-thread epilogue assignment: 2 hidden units ----
  const int rl = tid >> 2, ul2 = (tid & 3) * 2, bE = b0 + rl;
  const int hu = u * 8 + ul2;  // original hidden-unit index (pair base)
  const float Bi0 = J.bih[hu] + J.bhh[hu];
  const float Bi1 = J.bih[hu + 1] + J.bhh[hu + 1];
  const float Bf0 = J.bih[512 + hu] + J.bhh[512 + hu];
  const float Bf1 = J.bih[513 + hu] + J.bhh[513 + hu];
  const float Bg0 = J.bih[1024 + hu] + J.bhh[1024 + hu];
  const float Bg1 = J.bih[1025 + hu] + J.bhh[1025 + hu];
  const float Bo0 = J.bih[1536 + hu] + J.bhh[1536 + hu];
  const float Bo1 = J.bih[1537 + hu] + J.bhh[1537 + hu];
  {
    float c0v = 0.f, c1v = 0.f;
    if (J.c0) {
      c0v = J.c0[(size_t)bE * 512 + hu];
      c1v = J.c0[(size_t)bE * 512 + hu + 1];
    }
    cst[rl][ul2] = c0v;
    cst[rl][ul2 + 1] = c1v;
  }
  __syncthreads();

  const int mt = wv & 1, kh = wv >> 1;
  const int arow = b0 + mt * 32 + (ln & 31);
  const size_t hbase = (size_t)arow * 512 + (size_t)kh * 256 + ((ln >> 5) << 3);
  const uint16_t* wlh = Wl + (size_t)kh * HS + (size_t)ln * 8;
  const uint16_t* wlx = wlh + 16 * 512;
  const size_t hwr = (size_t)bE * 512 + hu;
  const int tsteps = J.tsteps;
  const uint32_t FB = J.fb;

  for (int t = 0; t < tsteps; ++t) {
    f32x16 acc;
#pragma unroll
    for (int r = 0; r < 16; ++r) acc[r] = 0.0f;

    // ---- x-part from global fp32 (enc0/dec0): no cross-WG dep -> pre-wait
    if (t < 512 && J.xring == nullptr) {
      const int tx = t - J.shift;
      if (tx >= 0) {
        const float* xb = J.xf + (size_t)arow * (512 * (size_t)KX) +
                          (size_t)tx * KX + kh * (KX >> 1) + ((ln >> 5) << 3);
        for (int kt = 0; kt < NTX; ++kt) {
          bf16x8 af = cvt8(xb + kt * 16);
          acc = MFMA32(af, *(const bf16x8*)(wlx + kt * 512), acc);
        }
      }
    }

    // ---- cross-WG flag waits: wave 0, one flag per lane, parallel poll ----
    if (wv == 0) {
      const uint32_t* po = J.fown + bg * 64;
      const uint32_t* pp = J.fprod ? J.fprod + bg * 64 : nullptr;
      const uint32_t* pc = J.fcons ? J.fcons + bg * 64 : nullptr;
      const uint32_t* pf = isfc ? J.fcons + (1 - bg) * 64 : nullptr;
      const int w_own = (t > 0) && (t <= 512);
      const int w_prod = (pp != nullptr) && (t < 512);
      const int w_cons = (pc != nullptr) && (t >= 4) && ((t < 512) || isfc);
      const int w_fc = (pf != nullptr) && (t >= 4);
      if (w_own || w_prod || w_cons || w_fc) {
        const uint32_t to = FB + (uint32_t)t;
        const uint32_t tp = to + 1u;
        const uint32_t tc = to - 3u;
        while (1) {
          int ok = 1;
          if (w_own)  ok &= (aldf(po + ln) >= to);
          if (w_prod) ok &= (aldf(pp + ln) >= tp);
          if (w_cons) ok &= (aldf(pc + ln) >= tc);
          if (w_fc)   ok &= (aldf(pf + ln) >= tc);
          if (__all(ok)) break;
          __builtin_amdgcn_s_sleep(1);
        }
      }
    }
    __syncthreads();

    if (t < 512) {
      // h-part: K 256 per half, from 8-plane bf16 ring (coherent loads,
      // all issued before the MFMA chain -> one IF$ round-trip)
      const uint16_t* hb = J.hring + (size_t)(t & 7) * 65536 + hbase;
      bf16x8 ah[16];
#pragma unroll
      for (int kt = 0; kt < 16; ++kt) ah[kt] = ald16(hb + kt * 16);
      if (J.xring) {  // previous layer's h ring (bf16, 512 wide)
        const uint16_t* xb = J.xring + (size_t)(t & 3) * 65536 + hbase;
        bf16x8 ax[16];
#pragma unroll
        for (int kt = 0; kt < 16; ++kt) ax[kt] = ald16(xb + kt * 16);
#pragma unroll
        for (int kt = 0; kt < 16; ++kt)
          acc = MFMA32(ah[kt], *(const bf16x8*)(wlh + kt * 512), acc);
#pragma unroll
        for (int kt = 0; kt < 16; ++kt)
          acc = MFMA32(ax[kt], *(const bf16x8*)(wlx + kt * 512), acc);
      } else {
#pragma unroll
        for (int kt = 0; kt < 16; ++kt)
          acc = MFMA32(ah[kt], *(const bf16x8*)(wlh + kt * 512), acc);
      }
#pragma unroll
      for (int r = 0; r < 16; ++r) {
        int crow = (r & 3) + 8 * (r >> 2) + 4 * (ln >> 5);
        gb[kh][mt * 32 + crow][ln & 31] = acc[r];
      }
      __syncthreads();

      // ---- epilogue: 2 hidden units per thread ----
      float i0 = sigm(gb[0][rl][ul2]      + gb[1][rl][ul2]      + Bi0);
      float i1 = sigm(gb[0][rl][ul2 + 1]  + gb[1][rl][ul2 + 1]  + Bi1);
      float f0 = sigm(gb[0][rl][8 + ul2]  + gb[1][rl][8 + ul2]  + Bf0);
      float f1 = sigm(gb[0][rl][9 + ul2]  + gb[1][rl][9 + ul2]  + Bf1);
      float g0 = tanh_f(gb[0][rl][16 + ul2] + gb[1][rl][16 + ul2] + Bg0);
      float g1 = tanh_f(gb[0][rl][17 + ul2] + gb[1][rl][17 + ul2] + Bg1);
      float o0 = sigm(gb[0][rl][24 + ul2] + gb[1][rl][24 + ul2] + Bo0);
      float o1 = sigm(gb[0][rl][25 + ul2] + gb[1][rl][25 + ul2] + Bo1);
      float cc0 = f0 * cst[rl][ul2]     + i0 * g0;
      float cc1 = f1 * cst[rl][ul2 + 1] + i1 * g1;
      cst[rl][ul2] = cc0;
      cst[rl][ul2 + 1] = cc1;
      float h0 = o0 * tanh_f(cc0);
      float h1 = o1 * tanh_f(cc1);
      uint32_t hv = (uint32_t)f2bf(h0) | ((uint32_t)f2bf(h1) << 16);
      // write-through device-coherent stores (sc0 sc1): no wbl2 needed later
      ast32(J.hring + (size_t)((t + 1) & 7) * 65536 + hwr, hv);
      if (J.ringout)
        ast32(J.ringout + (size_t)(t & 3) * 65536 + hwr, hv);

      // barrier drains every wave's vmcnt -> all sc0sc1 stores device-visible
      __syncthreads();
      if (tid == 0) {
        asm volatile("s_waitcnt vmcnt(0)" ::: "memory");
        __hip_atomic_store(J.fown + bg * 64 + u, FB + (uint32_t)(t + 1),
                           __ATOMIC_RELAXED, __HIP_MEMORY_SCOPE_AGENT);
      }
    }

    // ---- fused FC head: out[:, t-4] = dec1_h(t-4) @ fcW^T + fcb (fp32) ----
    if (isfc && t >= 4) {
      const int tf = t - 4;
      const uint16_t* ha = J.fchr + (size_t)((tf + 1) & 7) * 65536 +
                           (size_t)farow * 512 + ((ln >> 4) << 3);
      const uint16_t* wb = Wl + 32768 + (size_t)ln * 8;
      bf16x8 af[16];
#pragma unroll
      for (int kt = 0; kt < 16; ++kt) af[kt] = ald16(ha + kt * 32);
      f32x4 fa;
      fa[0] = fa[1] = fa[2] = fa[3] = 0.0f;
#pragma unroll
      for (int kt = 0; kt < 16; ++kt)
        fa = MFMA16(af[kt], *(const bf16x8*)(wb + kt * 512), fa);
#pragma unroll
      for (int r = 0; r < 4; ++r) {
        int row = ftr * 16 + ((ln >> 4) << 2) + r;  // batch index
        J.out[((size_t)row * 512 + tf) * 128 + fcol] = fa[r] + fbv;
      }
    }
  }
}

// ---------------- host launch ----------------
extern "C" void kernel_launch(void* const* d_in, const int* in_sizes, int n_in,
                              void* d_out, int out_size, void* d_ws, size_t ws_size,
                              hipStream_t stream) {
  (void)in_sizes; (void)n_in; (void)out_size; (void)ws_size;
  uint8_t* ws = (uint8_t*)d_ws;
  const float* x     = (const float*)d_in[0];
  const float* c_dec = (const float*)d_in[1];
  const float* W[16];
  for (int i = 0; i < 16; ++i) W[i] = (const float*)d_in[2 + i];
  // layer order in d_in: enc0{wih,whh,bih,bhh} enc1{...} dec0{...} dec1{...}
  const float* fcW = (const float*)d_in[18];
  const float* fcb = (const float*)d_in[19];

  uint32_t* FLG = (uint32_t*)(ws + OFF_FLG);
  uint16_t* HB0 = (uint16_t*)(ws + OFF_HB0);
  uint16_t* HB1 = (uint16_t*)(ws + OFF_HB1);
  uint16_t* E0R = (uint16_t*)(ws + OFF_E0R);
  uint16_t* D0R = (uint16_t*)(ws + OFF_D0R);
  // flag arrays: [2][64] for layer0 (enc0/dec0), [2][64] for layer1
  uint32_t* FL0 = FLG + 0;    // L0: bg0 [0..63], bg1 [64..127]
  uint32_t* FL1 = FLG + 128;  // L1: bg0 [0..63], bg1 [64..127]

  // 1) zero flags + h-ring plane0 (h_{-1} = 0)
  hipLaunchKernelGGL(init_kernel, dim3(128), dim3(256), 0, stream,
                     FLG, (uint32_t*)HB0, (uint32_t*)HB1);

  // 2) phase A: enc0 (x -> E0R, h in HB0) || enc1 (E0R -> HB1; seq discarded)
  {
    PJob a; a.whh = W[1]; a.wih = W[0]; a.bih = W[2]; a.bhh = W[3];
    a.xf = x; a.xring = nullptr; a.hring = HB0; a.c0 = nullptr; a.ringout = E0R;
    a.fown = FL0; a.fprod = nullptr; a.fcons = FL1;
    a.fcw = nullptr; a.fcb = nullptr; a.fchr = nullptr; a.out = nullptr;
    a.KX = 128; a.shift = 0; a.tsteps = 512; a.fb = 0;
    PJob b; b.whh = W[5]; b.wih = W[4]; b.bih = W[6]; b.bhh = W[7];
    b.xf = nullptr; b.xring = E0R; b.hring = HB1; b.c0 = nullptr; b.ringout = nullptr;
    b.fown = FL1; b.fprod = FL0; b.fcons = nullptr;
    b.fcw = nullptr; b.fcb = nullptr; b.fchr = nullptr; b.out = nullptr;
    b.KX = 512; b.shift = 0; b.tsteps = 512; b.fb = 0;
    void* args[2] = { &a, &b };
    hipLaunchCooperativeKernel((const void*)lstm_pipe, dim3(256), dim3(256), args, 0, stream);
  }

  // 3) phase B: dec0 (shift(x) -> D0R, h0 = enc0 hT in HB0 plane0, c0=c_dec[0],
  //    + fused FC from dec1's ring) || dec1 (D0R -> HB1, h0 = enc1 hT, c0=c_dec[1])
  //    Flag arrays reused with fb=512 (phase A leaves every flag at exactly 512).
  {
    PJob a; a.whh = W[9]; a.wih = W[8]; a.bih = W[10]; a.bhh = W[11];
    a.xf = x; a.xring = nullptr; a.hring = HB0; a.c0 = c_dec; a.ringout = D0R;
    a.fown = FL0; a.fprod = nullptr; a.fcons = FL1;
    a.fcw = fcW; a.fcb = fcb; a.fchr = HB1; a.out = (float*)d_out;
    a.KX = 128; a.shift = 1; a.tsteps = 516; a.fb = 512;
    PJob b; b.whh = W[13]; b.wih = W[12]; b.bih = W[14]; b.bhh = W[15];
    b.xf = nullptr; b.xring = D0R; b.hring = HB1; b.c0 = c_dec + 65536; b.ringout = nullptr;
    b.fown = FL1; b.fprod = FL0; b.fcons = nullptr;
    b.fcw = nullptr; b.fcb = nullptr; b.fchr = nullptr; b.out = nullptr;
    b.KX = 512; b.shift = 0; b.tsteps = 512; b.fb = 512;
    void* args[2] = { &a, &b };
    hipLaunchCooperativeKernel((const void*)lstm_pipe, dim3(256), dim3(256), args, 0, stream);
  }
}